// Round 3
// baseline (577.937 us; speedup 1.0000x reference)
//
#include <hip/hip_runtime.h>
#include <math.h>

#define NEG_SLOPE 0.2f

typedef short s16x8 __attribute__((ext_vector_type(8)));
typedef float f32x16 __attribute__((ext_vector_type(16)));

// float -> bf16 (round-to-nearest-even), and back
__device__ __forceinline__ unsigned short f2bf(float x){
  unsigned int u = __float_as_uint(x);
  unsigned int r = u + 0x7FFFu + ((u >> 16) & 1u);
  return (unsigned short)(r >> 16);
}
__device__ __forceinline__ float bf2f(unsigned short h){
  return __uint_as_float(((unsigned int)h) << 16);
}

// ---------------------------------------------------------------- CSR build
__global__ void deg_count_kernel(const int* __restrict__ dst, int* __restrict__ deg, int E){
  int e = blockIdx.x * blockDim.x + threadIdx.x;
  if (e < E) atomicAdd(&deg[dst[e]], 1);
}

__global__ void base_assign_kernel(const int* __restrict__ deg, int* __restrict__ base,
                                   int* __restrict__ counter, int N){
  int n = blockIdx.x * blockDim.x + threadIdx.x;
  if (n < N) base[n] = atomicAdd(counter, deg[n]);
}

__global__ void fill_kernel(const int* __restrict__ ei, const float* __restrict__ ea,
                            const int* __restrict__ base, int* __restrict__ pos,
                            int2* __restrict__ csr_pack, int E){
  int e = blockIdx.x * blockDim.x + threadIdx.x;
  if (e >= E) return;
  int s = ei[e], d = ei[E + e];
  int p = atomicAdd(&pos[d], 1);
  csr_pack[base[d] + p] = make_int2(s, __float_as_int(ea[e]));
}

// ---------------------------------------------------------------- weight prep
// Pack W1|W2 (each [K][NOUT] fp32 row-major) into bf16 hi/lo arrays laid out as
// [kgroup][col(2*NOUT)][8 k-elems] -- exactly the MFMA B-fragment order, so the
// GEMM reads B fragments as fully-coalesced 16B-per-lane global loads.
__device__ __forceinline__ void pack_pair(const float* __restrict__ W1,
                                          const float* __restrict__ W2,
                                          short* __restrict__ H, short* __restrict__ L,
                                          int id, int K, int NOUT){
  int BN = 2 * NOUT;
  int kg = id / BN, cb = id - kg * BN;
  const float* W = (cb < NOUT) ? W1 : W2;
  int c = (cb < NOUT) ? cb : cb - NOUT;
  s16x8 hv, lv;
  #pragma unroll
  for (int e = 0; e < 8; e++){
    int k = kg * 8 + e;
    float v = (k < K) ? W[(long)k * NOUT + c] : 0.f;
    unsigned short h = f2bf(v);
    hv[e] = (short)h;
    lv[e] = (short)f2bf(v - bf2f(h));
  }
  *(s16x8*)&H[(long)id * 8] = hv;
  *(s16x8*)&L[(long)id * 8] = lv;
}

__global__ void prep_w_kernel(const float* Wl1, const float* Wr1, short* H1, short* L1,
                              const float* Wl2, const float* Wr2, short* H2, short* L2,
                              const float* Wl3, const float* Wr3, short* H3, short* L3,
                              const float* Wl4, const float* Wr4, short* H4, short* L4){
  int id = blockIdx.x * blockDim.x + threadIdx.x;
  if (id < 512)  { pack_pair(Wl1, Wr1, H1, L1, id, 15, 128); return; }   // KG=2,  BN=256
  id -= 512;
  if (id < 4096) { pack_pair(Wl2, Wr2, H2, L2, id, 128, 128); return; }  // KG=16, BN=256
  id -= 4096;
  if (id < 4096) { pack_pair(Wl3, Wr3, H3, L3, id, 128, 128); return; }
  id -= 4096;
  if (id < 2048) { pack_pair(Wl4, Wr4, H4, L4, id, 128, 64); return; }   // KG=16, BN=128
}

// ---------------------------------------------------------------- MFMA dual GEMM
// Y1 = X@W1 + b1, Y2 = X@W2 + b2 via split-bf16 3-product emulation:
//   X = Xh + Xl, W = Wh + Wl (bf16 each); Y ~= Xh*Wh + Xh*Wl + Xl*Wh (fp32 acc).
// R3 redesign: NO LDS, NO barriers (R2's 83KB LDS -> 1 block/CU -> ~6% MfmaUtil).
//   A: each lane holds its row's half-K in registers, converted hi/lo ONCE.
//   B: prepacked fragments read straight from global (coalesced 16B/lane,
//      L2-resident, shared by all blocks). Each wave = independent MFMA stream.
// Fragment layouts (gfx950 v_mfma_f32_32x32x16_bf16):
//   A: row = lane&31, k = 8*(lane>>5)+e     B: col = lane&31, k = 8*(lane>>5)+e
//   D: col = lane&31, row = (reg&3) + 8*(reg>>2) + 4*(lane>>5)
template<int NOUT, int K>
__global__ __launch_bounds__(256, 2) void gemm_dual_mfma(
    const float* __restrict__ X,
    const short* __restrict__ BH, const short* __restrict__ BL,
    const float* __restrict__ b1, const float* __restrict__ b2,
    float* __restrict__ Y1, float* __restrict__ Y2, int N)
{
  constexpr int BN     = 2 * NOUT;
  constexpr int KSTEPS = (K + 15) / 16;     // one 32x32x16 MFMA step each
  constexpr int NR     = NOUT / 32;         // col fragments per wave (4 or 2)

  int tid   = threadIdx.x;
  int lane  = tid & 63;
  int wid   = tid >> 6;
  int wm    = wid >> 1, wn = wid & 1;       // block = 64 rows x (Y1|Y2)
  int llane = lane & 31, hlane = lane >> 5;
  int r0    = blockIdx.x * 64;

  // ---- A: load this lane's row (half-K per lane-half), convert hi/lo once
  int arow  = r0 + wm * 32 + llane;
  bool rv   = arow < N;
  const float* px = X + (long)arow * K;

  s16x8 ah[KSTEPS], al[KSTEPS];
  #pragma unroll
  for (int ks = 0; ks < KSTEPS; ks++){
    int kg = (2 * ks + hlane) * 8;
    float v[8];
    if constexpr (K % 8 == 0){
      float4 p0 = {0.f,0.f,0.f,0.f}, p1 = {0.f,0.f,0.f,0.f};
      if (rv){
        p0 = *(const float4*)(px + kg);
        p1 = *(const float4*)(px + kg + 4);
      }
      v[0]=p0.x; v[1]=p0.y; v[2]=p0.z; v[3]=p0.w;
      v[4]=p1.x; v[5]=p1.y; v[6]=p1.z; v[7]=p1.w;
    } else {
      #pragma unroll
      for (int e = 0; e < 8; e++)
        v[e] = (rv && kg + e < K) ? px[kg + e] : 0.f;
    }
    #pragma unroll
    for (int e = 0; e < 8; e++){
      unsigned short h = f2bf(v[e]);
      ah[ks][e] = (short)h;
      al[ks][e] = (short)f2bf(v[e] - bf2f(h));
    }
  }

  f32x16 acc[NR];
  #pragma unroll
  for (int n = 0; n < NR; n++)
    #pragma unroll
    for (int i = 0; i < 16; i++) acc[n][i] = 0.f;

  // ---- K loop: B fragments straight from global, 3*NR MFMA per kstep
  const s16x8* BHf = (const s16x8*)BH;
  const s16x8* BLf = (const s16x8*)BL;
  #pragma unroll
  for (int ks = 0; ks < KSTEPS; ks++){
    long fb = (long)(2 * ks + hlane) * BN + wn * NOUT + llane;
    s16x8 bh[NR], bl[NR];
    #pragma unroll
    for (int n = 0; n < NR; n++){
      bh[n] = BHf[fb + n * 32];
      bl[n] = BLf[fb + n * 32];
    }
    #pragma unroll
    for (int n = 0; n < NR; n++)
      acc[n] = __builtin_amdgcn_mfma_f32_32x32x16_bf16(ah[ks], bh[n], acc[n], 0, 0, 0);
    #pragma unroll
    for (int n = 0; n < NR; n++)
      acc[n] = __builtin_amdgcn_mfma_f32_32x32x16_bf16(ah[ks], bl[n], acc[n], 0, 0, 0);
    #pragma unroll
    for (int n = 0; n < NR; n++)
      acc[n] = __builtin_amdgcn_mfma_f32_32x32x16_bf16(al[ks], bh[n], acc[n], 0, 0, 0);
  }

  // ---- epilogue: bias + store (wave wn=0 -> Y1, wn=1 -> Y2)
  const float* bsrc = wn ? b2 : b1;
  float* Y = wn ? Y2 : Y1;
  #pragma unroll
  for (int n = 0; n < NR; n++){
    float bias = bsrc[n * 32 + llane];
    #pragma unroll
    for (int reg = 0; reg < 16; reg++){
      int row = r0 + wm * 32 + (reg & 3) + 8 * (reg >> 2) + 4 * hlane;
      if (row < N)
        Y[(long)row * NOUT + n * 32 + llane] = acc[n][reg] + bias;
    }
  }
}

// ---------------------------------------------------------------- fused edge softmax + aggregation
// One wave per dst node (grid-stride). Lane = (edge-slot, head, channel-quad):
// LPE = lanes per edge (32 for C=16, 16 for C=8) -> each row read is fully
// contiguous (512/256 B) b128 per lane. No-max softmax (logits O(1); exp is
// algebraically identical to ref's max-subtracted form) -> no cross-batch
// serial dependency, loads prefetch ahead. Optional fused final linear.
// NOTE (R1 post-mortem): do NOT predicate the NP loads on tail occupancy --
// wrapping them in `if (t < nt)` broke the 8-deep load batching and cost +50%
// (VALUBusy 53->32, BW 3.1->2.1 TB/s). Unconditional dummy loads are cheaper.
template<int C>
__global__ __launch_bounds__(512) void agg_kernel(
    const float* __restrict__ xl, const float* __restrict__ xr,
    const int* __restrict__ base, const int* __restrict__ deg,
    const int2* __restrict__ csr_pack,
    const float* __restrict__ We, const float* __restrict__ att,
    const float* __restrict__ bias, float* __restrict__ hout,
    const float* __restrict__ Wlin, const float* __restrict__ blin,
    float* __restrict__ outF, int N, int do_elu)
{
  constexpr int HC  = 8 * C;
  constexpr int LPH = C / 4;       // lanes per head
  constexpr int LPE = 8 * LPH;     // lanes per edge (32 or 16)
  constexpr int ES  = 64 / LPE;    // edge slots per pass (2 or 4)
  constexpr int NP  = 4;           // passes per iteration
  constexpr int B   = ES * NP;     // edges per iteration (8 or 16)

  int lane = threadIdx.x & 63;
  int wv   = blockIdx.x * (blockDim.x >> 6) + (threadIdx.x >> 6);
  int nwv  = gridDim.x * (blockDim.x >> 6);
  int slot = lane / LPE;           // edge slot within pass
  int hl   = lane % LPE;           // position within edge
  int coff = hl * 4;               // channel offset: h*C + g*4 == hl*4

  float4 attv = *(const float4*)(att  + coff);
  float4 wev  = *(const float4*)(We   + coff);
  float4 bv   = *(const float4*)(bias + coff);
  float4 wl   = outF ? *(const float4*)(Wlin + coff) : make_float4(0.f,0.f,0.f,0.f);

  for (int n = wv; n < N; n += nwv){
    float4 xrv = *(const float4*)(xr + (long)n * HC + coff);
    float4 acc = {0.f, 0.f, 0.f, 0.f};
    float lrun = 0.f;
    int s0 = base[n], end = s0 + deg[n];

    for (int s = s0; s < end; s += B){
      int2 pk[NP]; bool val[NP];
      #pragma unroll
      for (int t = 0; t < NP; t++){
        int idx = s + t * ES + slot;
        val[t] = idx < end;
        pk[t]  = csr_pack[val[t] ? idx : s0];
      }
      float4 row[NP];
      #pragma unroll
      for (int t = 0; t < NP; t++)
        row[t] = *(const float4*)(xl + (long)pk[t].x * HC + coff);
      #pragma unroll
      for (int t = 0; t < NP; t++){
        float eav = __int_as_float(pk[t].y);
        float t0 = row[t].x + xrv.x + eav * wev.x;
        float t1 = row[t].y + xrv.y + eav * wev.y;
        float t2 = row[t].z + xrv.z + eav * wev.z;
        float t3 = row[t].w + xrv.w + eav * wev.w;
        float m0 = fmaxf(t0, 0.f) + NEG_SLOPE * fminf(t0, 0.f);
        float m1 = fmaxf(t1, 0.f) + NEG_SLOPE * fminf(t1, 0.f);
        float m2 = fmaxf(t2, 0.f) + NEG_SLOPE * fminf(t2, 0.f);
        float m3 = fmaxf(t3, 0.f) + NEG_SLOPE * fminf(t3, 0.f);
        float p = ((m0 * attv.x + m1 * attv.y) + (m2 * attv.z + m3 * attv.w));
        #pragma unroll
        for (int o = 1; o < LPH; o <<= 1) p += __shfl_xor(p, o);
        float pe = val[t] ? __expf(p) : 0.f;
        lrun  += pe;
        acc.x += pe * row[t].x;
        acc.y += pe * row[t].y;
        acc.z += pe * row[t].z;
        acc.w += pe * row[t].w;
      }
    }
    // reduce over edge slots
    #pragma unroll
    for (int o = LPE; o < 64; o <<= 1){
      lrun  += __shfl_xor(lrun, o);
      acc.x += __shfl_xor(acc.x, o);
      acc.y += __shfl_xor(acc.y, o);
      acc.z += __shfl_xor(acc.z, o);
      acc.w += __shfl_xor(acc.w, o);
    }
    float inv = 1.f / (lrun + 1e-16f);
    float4 o4;
    o4.x = acc.x * inv + bv.x;
    o4.y = acc.y * inv + bv.y;
    o4.z = acc.z * inv + bv.z;
    o4.w = acc.w * inv + bv.w;
    if (do_elu){
      o4.x = o4.x > 0.f ? o4.x : (__expf(o4.x) - 1.f);
      o4.y = o4.y > 0.f ? o4.y : (__expf(o4.y) - 1.f);
      o4.z = o4.z > 0.f ? o4.z : (__expf(o4.z) - 1.f);
      o4.w = o4.w > 0.f ? o4.w : (__expf(o4.w) - 1.f);
    }
    if (outF){
      // fused final linear: out[n] = sum_c o_c * Wlin_c + blin
      float v = ((o4.x * wl.x + o4.y * wl.y) + (o4.z * wl.z + o4.w * wl.w));
      #pragma unroll
      for (int o = 1; o < LPE; o <<= 1) v += __shfl_xor(v, o);
      if (lane == 0) outF[n] = v + blin[0];
    } else {
      if (slot == 0)
        *(float4*)(hout + (long)n * HC + coff) = o4;
    }
  }
}

// ----------------------------------------------------------------
extern "C" void kernel_launch(void* const* d_in, const int* in_sizes, int n_in,
                              void* d_out, int out_size, void* d_ws, size_t ws_size,
                              hipStream_t stream)
{
  const float* x  = (const float*)d_in[0];
  const float* ea = (const float*)d_in[1];
  const int*   ei = (const int*)d_in[2];
  const int N = in_sizes[0] / 15;
  const int E = in_sizes[1];

  const float* P[28];
  for (int i = 0; i < 28; i++) P[i] = (const float*)d_in[3 + i];
  const float* Wlin = (const float*)d_in[31];
  const float* blin = (const float*)d_in[32];

  size_t off = 0;
  auto carve = [&](size_t bytes) -> char* {
    char* p = (char*)d_ws + off;
    off = (off + bytes + 255) & ~(size_t)255;
    return p;
  };
  int*   meta     = (int*)  carve(sizeof(int)  * (size_t)(3 * N + 64));
  int*   deg      = meta;                // [N] zeroed
  int*   pos      = meta + N;            // [N] zeroed
  int*   base     = meta + 2 * N;        // [N]
  int*   counter  = meta + 3 * N;        // [1] zeroed
  int2*  csr_pack = (int2*) carve(sizeof(int2) * (size_t)E);
  float* xl       = (float*)carve(sizeof(float) * (size_t)N * 128);
  float* xr       = (float*)carve(sizeof(float) * (size_t)N * 128);
  float* hA       = (float*)carve(sizeof(float) * (size_t)N * 128);
  float* hB       = (float*)carve(sizeof(float) * (size_t)N * 128);
  // prepacked bf16 hi/lo weights, MFMA B-fragment order
  short* ph1 = (short*)carve(sizeof(short) * 4096);
  short* pl1 = (short*)carve(sizeof(short) * 4096);
  short* ph2 = (short*)carve(sizeof(short) * 32768);
  short* pl2 = (short*)carve(sizeof(short) * 32768);
  short* ph3 = (short*)carve(sizeof(short) * 32768);
  short* pl3 = (short*)carve(sizeof(short) * 32768);
  short* ph4 = (short*)carve(sizeof(short) * 16384);
  short* pl4 = (short*)carve(sizeof(short) * 16384);

  hipMemsetAsync(deg,     0, sizeof(int) * (size_t)(2 * N), stream);
  hipMemsetAsync(counter, 0, sizeof(int), stream);

  int eb = (E + 255) / 256;
  int nb = (N + 255) / 256;
  deg_count_kernel  <<<eb, 256, 0, stream>>>(ei + E, deg, E);
  base_assign_kernel<<<nb, 256, 0, stream>>>(deg, base, counter, N);
  fill_kernel       <<<eb, 256, 0, stream>>>(ei, ea, base, pos, csr_pack, E);
  prep_w_kernel     <<<42, 256, 0, stream>>>(P[0],  P[2],  ph1, pl1,
                                             P[7],  P[9],  ph2, pl2,
                                             P[14], P[16], ph3, pl3,
                                             P[21], P[23], ph4, pl4);

  int gm    = (N + 63) / 64;  // 64-row MFMA tiles
  int agrid = 2048;           // agg: grid-stride, 8 waves/block

  // layer 1: din=15, H*C=128, ELU
  gemm_dual_mfma<128, 15><<<gm, 256, 0, stream>>>(x, ph1, pl1, P[1], P[3], xl, xr, N);
  agg_kernel<16><<<agrid, 512, 0, stream>>>(xl, xr, base, deg, csr_pack, P[4], P[5], P[6], hA,
                                            nullptr, nullptr, nullptr, N, 1);
  // layer 2: din=128, ELU
  gemm_dual_mfma<128, 128><<<gm, 256, 0, stream>>>(hA, ph2, pl2, P[8], P[10], xl, xr, N);
  agg_kernel<16><<<agrid, 512, 0, stream>>>(xl, xr, base, deg, csr_pack, P[11], P[12], P[13], hB,
                                            nullptr, nullptr, nullptr, N, 1);
  // layer 3: din=128, ELU
  gemm_dual_mfma<128, 128><<<gm, 256, 0, stream>>>(hB, ph3, pl3, P[15], P[17], xl, xr, N);
  agg_kernel<16><<<agrid, 512, 0, stream>>>(xl, xr, base, deg, csr_pack, P[18], P[19], P[20], hA,
                                            nullptr, nullptr, nullptr, N, 1);
  // layer 4: din=128, H*C=64, no ELU + fused final linear 64->1
  gemm_dual_mfma<64, 128><<<gm, 256, 0, stream>>>(hA, ph4, pl4, P[22], P[24], xl, xr, N);
  agg_kernel<8><<<agrid, 512, 0, stream>>>(xl, xr, base, deg, csr_pack, P[25], P[26], P[27], hB,
                                           Wlin, blin, (float*)d_out, N, 0);
}

// Round 4
// 534.456 us; speedup vs baseline: 1.0814x; 1.0814x over previous
//
#include <hip/hip_runtime.h>
#include <math.h>

#define NEG_SLOPE 0.2f

typedef short s16x4 __attribute__((ext_vector_type(4)));
typedef short s16x8 __attribute__((ext_vector_type(8)));
typedef float f32x16 __attribute__((ext_vector_type(16)));

// float -> bf16 (round-to-nearest-even), and back
__device__ __forceinline__ unsigned short f2bf(float x){
  unsigned int u = __float_as_uint(x);
  unsigned int r = u + 0x7FFFu + ((u >> 16) & 1u);
  return (unsigned short)(r >> 16);
}
__device__ __forceinline__ float bf2f(unsigned short h){
  return __uint_as_float(((unsigned int)h) << 16);
}

// ---------------------------------------------------------------- CSR build
__global__ void deg_count_kernel(const int* __restrict__ dst, int* __restrict__ deg, int E){
  int e = blockIdx.x * blockDim.x + threadIdx.x;
  if (e < E) atomicAdd(&deg[dst[e]], 1);
}

__global__ void base_assign_kernel(const int* __restrict__ deg, int* __restrict__ base,
                                   int* __restrict__ counter, int N){
  int n = blockIdx.x * blockDim.x + threadIdx.x;
  if (n < N) base[n] = atomicAdd(counter, deg[n]);
}

__global__ void fill_kernel(const int* __restrict__ ei, const float* __restrict__ ea,
                            const int* __restrict__ base, int* __restrict__ pos,
                            int2* __restrict__ csr_pack, int E){
  int e = blockIdx.x * blockDim.x + threadIdx.x;
  if (e >= E) return;
  int s = ei[e], d = ei[E + e];
  int p = atomicAdd(&pos[d], 1);
  csr_pack[base[d] + p] = make_int2(s, __float_as_int(ea[e]));
}

// ---------------------------------------------------------------- weight prep
// Pack W1|W2 (each [K][NOUT] fp32 row-major) into bf16 hi/lo arrays laid out as
// [kgroup][col(2*NOUT)][8 k-elems] -- exactly the MFMA B-fragment order, so the
// GEMM reads B fragments as fully-coalesced 16B-per-lane global loads.
__device__ __forceinline__ void pack_pair(const float* __restrict__ W1,
                                          const float* __restrict__ W2,
                                          short* __restrict__ H, short* __restrict__ L,
                                          int id, int K, int NOUT){
  int BN = 2 * NOUT;
  int kg = id / BN, cb = id - kg * BN;
  const float* W = (cb < NOUT) ? W1 : W2;
  int c = (cb < NOUT) ? cb : cb - NOUT;
  s16x8 hv, lv;
  #pragma unroll
  for (int e = 0; e < 8; e++){
    int k = kg * 8 + e;
    float v = (k < K) ? W[(long)k * NOUT + c] : 0.f;
    unsigned short h = f2bf(v);
    hv[e] = (short)h;
    lv[e] = (short)f2bf(v - bf2f(h));
  }
  *(s16x8*)&H[(long)id * 8] = hv;
  *(s16x8*)&L[(long)id * 8] = lv;
}

__global__ void prep_w_kernel(const float* Wl1, const float* Wr1, short* H1, short* L1,
                              const float* Wl2, const float* Wr2, short* H2, short* L2,
                              const float* Wl3, const float* Wr3, short* H3, short* L3,
                              const float* Wl4, const float* Wr4, short* H4, short* L4){
  int id = blockIdx.x * blockDim.x + threadIdx.x;
  if (id < 512)  { pack_pair(Wl1, Wr1, H1, L1, id, 15, 128); return; }   // KG=2,  BN=256
  id -= 512;
  if (id < 4096) { pack_pair(Wl2, Wr2, H2, L2, id, 128, 128); return; }  // KG=16, BN=256
  id -= 4096;
  if (id < 4096) { pack_pair(Wl3, Wr3, H3, L3, id, 128, 128); return; }
  id -= 4096;
  if (id < 2048) { pack_pair(Wl4, Wr4, H4, L4, id, 128, 64); return; }   // KG=16, BN=128
}

// ---------------------------------------------------------------- MFMA dual GEMM (layer 1, K=15)
// A gathered+converted in-kernel (cheap at K=15: 1 kstep). See gemm_dual_packed
// for the K=128 layers where the gather/convert cost was the bottleneck.
// Fragment layouts (gfx950 v_mfma_f32_32x32x16_bf16):
//   A: row = lane&31, k = 8*(lane>>5)+e     B: col = lane&31, k = 8*(lane>>5)+e
//   D: col = lane&31, row = (reg&3) + 8*(reg>>2) + 4*(lane>>5)
template<int NOUT, int K>
__global__ __launch_bounds__(256) void gemm_dual_mfma(
    const float* __restrict__ X,
    const short* __restrict__ BH, const short* __restrict__ BL,
    const float* __restrict__ b1, const float* __restrict__ b2,
    float* __restrict__ Y1, float* __restrict__ Y2, int N)
{
  constexpr int BN     = 2 * NOUT;
  constexpr int KSTEPS = (K + 15) / 16;     // one 32x32x16 MFMA step each
  constexpr int NR     = NOUT / 32;         // col fragments per wave (4 or 2)

  int tid   = threadIdx.x;
  int lane  = tid & 63;
  int wid   = tid >> 6;
  int wm    = wid >> 1, wn = wid & 1;       // block = 64 rows x (Y1|Y2)
  int llane = lane & 31, hlane = lane >> 5;
  int r0    = blockIdx.x * 64;

  // ---- A: load this lane's row (half-K per lane-half), convert hi/lo once
  int arow  = r0 + wm * 32 + llane;
  bool rv   = arow < N;
  const float* px = X + (long)arow * K;

  s16x8 ah[KSTEPS], al[KSTEPS];
  #pragma unroll
  for (int ks = 0; ks < KSTEPS; ks++){
    int kg = (2 * ks + hlane) * 8;
    float v[8];
    if constexpr (K % 8 == 0){
      float4 p0 = {0.f,0.f,0.f,0.f}, p1 = {0.f,0.f,0.f,0.f};
      if (rv){
        p0 = *(const float4*)(px + kg);
        p1 = *(const float4*)(px + kg + 4);
      }
      v[0]=p0.x; v[1]=p0.y; v[2]=p0.z; v[3]=p0.w;
      v[4]=p1.x; v[5]=p1.y; v[6]=p1.z; v[7]=p1.w;
    } else {
      #pragma unroll
      for (int e = 0; e < 8; e++)
        v[e] = (rv && kg + e < K) ? px[kg + e] : 0.f;
    }
    #pragma unroll
    for (int e = 0; e < 8; e++){
      unsigned short h = f2bf(v[e]);
      ah[ks][e] = (short)h;
      al[ks][e] = (short)f2bf(v[e] - bf2f(h));
    }
  }

  f32x16 acc[NR];
  #pragma unroll
  for (int n = 0; n < NR; n++)
    #pragma unroll
    for (int i = 0; i < 16; i++) acc[n][i] = 0.f;

  const s16x8* BHf = (const s16x8*)BH;
  const s16x8* BLf = (const s16x8*)BL;
  #pragma unroll
  for (int ks = 0; ks < KSTEPS; ks++){
    long fb = (long)(2 * ks + hlane) * BN + wn * NOUT + llane;
    s16x8 bh[NR], bl[NR];
    #pragma unroll
    for (int n = 0; n < NR; n++){
      bh[n] = BHf[fb + n * 32];
      bl[n] = BLf[fb + n * 32];
    }
    #pragma unroll
    for (int n = 0; n < NR; n++)
      acc[n] = __builtin_amdgcn_mfma_f32_32x32x16_bf16(ah[ks], bh[n], acc[n], 0, 0, 0);
    #pragma unroll
    for (int n = 0; n < NR; n++)
      acc[n] = __builtin_amdgcn_mfma_f32_32x32x16_bf16(ah[ks], bl[n], acc[n], 0, 0, 0);
    #pragma unroll
    for (int n = 0; n < NR; n++)
      acc[n] = __builtin_amdgcn_mfma_f32_32x32x16_bf16(al[ks], bh[n], acc[n], 0, 0, 0);
  }

  const float* bsrc = wn ? b2 : b1;
  float* Y = wn ? Y2 : Y1;
  #pragma unroll
  for (int n = 0; n < NR; n++){
    float bias = bsrc[n * 32 + llane];
    #pragma unroll
    for (int reg = 0; reg < 16; reg++){
      int row = r0 + wm * 32 + (reg & 3) + 8 * (reg >> 2) + 4 * hlane;
      if (row < N)
        Y[(long)row * NOUT + n * 32 + llane] = acc[n][reg] + bias;
    }
  }
}

// ---------------------------------------------------------------- packed-A MFMA dual GEMM (K=128)
// A comes prepacked in fragment order [kgroup][row][8k] (bf16 hi/lo), written by
// the previous layer's agg epilogue at zero extra traffic. Both operands are
// fully-coalesced 16B/lane streams; no LDS, no barriers, no in-kernel convert.
// R3 post-mortem: the in-gemm 64-row gather + hi/lo convert at ~2 waves/SIMD
// kept the gemm latency-bound at ~55us; this removes all of it.
template<int NOUT>
__global__ __launch_bounds__(256) void gemm_dual_packed(
    const short* __restrict__ AH, const short* __restrict__ AL,
    const short* __restrict__ BH, const short* __restrict__ BL,
    const float* __restrict__ b1, const float* __restrict__ b2,
    float* __restrict__ Y1, float* __restrict__ Y2, int N)
{
  constexpr int BN     = 2 * NOUT;
  constexpr int KSTEPS = 8;                 // K = 128
  constexpr int NR     = NOUT / 32;

  int tid   = threadIdx.x;
  int lane  = tid & 63;
  int wid   = tid >> 6;
  int wm    = wid >> 1, wn = wid & 1;
  int llane = lane & 31, hlane = lane >> 5;
  int r0    = blockIdx.x * 64;
  int arow  = r0 + wm * 32 + llane;
  int ar    = arow < N ? arow : N - 1;      // clamp: extra rows never stored

  const s16x8* AHf = (const s16x8*)AH;
  const s16x8* ALf = (const s16x8*)AL;
  const s16x8* BHf = (const s16x8*)BH;
  const s16x8* BLf = (const s16x8*)BL;

  f32x16 acc[NR];
  #pragma unroll
  for (int n = 0; n < NR; n++)
    #pragma unroll
    for (int i = 0; i < 16; i++) acc[n][i] = 0.f;

  #pragma unroll
  for (int ks = 0; ks < KSTEPS; ks++){
    long fa = (long)(2 * ks + hlane) * N + ar;
    s16x8 ah = AHf[fa];
    s16x8 al = ALf[fa];
    long fb = (long)(2 * ks + hlane) * BN + wn * NOUT + llane;
    s16x8 bh[NR], bl[NR];
    #pragma unroll
    for (int n = 0; n < NR; n++){
      bh[n] = BHf[fb + n * 32];
      bl[n] = BLf[fb + n * 32];
    }
    #pragma unroll
    for (int n = 0; n < NR; n++)
      acc[n] = __builtin_amdgcn_mfma_f32_32x32x16_bf16(ah, bh[n], acc[n], 0, 0, 0);
    #pragma unroll
    for (int n = 0; n < NR; n++)
      acc[n] = __builtin_amdgcn_mfma_f32_32x32x16_bf16(ah, bl[n], acc[n], 0, 0, 0);
    #pragma unroll
    for (int n = 0; n < NR; n++)
      acc[n] = __builtin_amdgcn_mfma_f32_32x32x16_bf16(al, bh[n], acc[n], 0, 0, 0);
  }

  const float* bsrc = wn ? b2 : b1;
  float* Y = wn ? Y2 : Y1;
  #pragma unroll
  for (int n = 0; n < NR; n++){
    float bias = bsrc[n * 32 + llane];
    #pragma unroll
    for (int reg = 0; reg < 16; reg++){
      int row = r0 + wm * 32 + (reg & 3) + 8 * (reg >> 2) + 4 * hlane;
      if (row < N)
        Y[(long)row * NOUT + n * 32 + llane] = acc[n][reg] + bias;
    }
  }
}

// ---------------------------------------------------------------- fused edge softmax + aggregation
// One wave per dst node (grid-stride). Lane = (edge-slot, head, channel-quad):
// LPE = lanes per edge (32 for C=16, 16 for C=8) -> each row read is fully
// contiguous (512/256 B) b128 per lane. No-max softmax (logits O(1); exp is
// algebraically identical to ref's max-subtracted form) -> no cross-batch
// serial dependency, loads prefetch ahead. Optional fused final linear.
// NOTE (R1 post-mortem): do NOT predicate the NP loads on tail occupancy --
// wrapping them in `if (t < nt)` broke the 8-deep load batching and cost +50%
// (VALUBusy 53->32, BW 3.1->2.1 TB/s). Unconditional dummy loads are cheaper.
// NEW (R4): when packH != null (C=16 layers feeding a K=128 gemm), the epilogue
// writes the output row as bf16 hi/lo MFMA A-fragments (same total bytes as the
// fp32 hout it replaces) so the next gemm streams A coalesced with no convert.
template<int C>
__global__ __launch_bounds__(512) void agg_kernel(
    const float* __restrict__ xl, const float* __restrict__ xr,
    const int* __restrict__ base, const int* __restrict__ deg,
    const int2* __restrict__ csr_pack,
    const float* __restrict__ We, const float* __restrict__ att,
    const float* __restrict__ bias, float* __restrict__ hout,
    short* __restrict__ packH, short* __restrict__ packL,
    const float* __restrict__ Wlin, const float* __restrict__ blin,
    float* __restrict__ outF, int N, int do_elu)
{
  constexpr int HC  = 8 * C;
  constexpr int LPH = C / 4;       // lanes per head
  constexpr int LPE = 8 * LPH;     // lanes per edge (32 or 16)
  constexpr int ES  = 64 / LPE;    // edge slots per pass (2 or 4)
  constexpr int NP  = 4;           // passes per iteration
  constexpr int B   = ES * NP;     // edges per iteration (8 or 16)

  int lane = threadIdx.x & 63;
  int wv   = blockIdx.x * (blockDim.x >> 6) + (threadIdx.x >> 6);
  int nwv  = gridDim.x * (blockDim.x >> 6);
  int slot = lane / LPE;           // edge slot within pass
  int hl   = lane % LPE;           // position within edge
  int coff = hl * 4;               // channel offset: h*C + g*4 == hl*4

  float4 attv = *(const float4*)(att  + coff);
  float4 wev  = *(const float4*)(We   + coff);
  float4 bv   = *(const float4*)(bias + coff);
  float4 wl   = outF ? *(const float4*)(Wlin + coff) : make_float4(0.f,0.f,0.f,0.f);

  for (int n = wv; n < N; n += nwv){
    float4 xrv = *(const float4*)(xr + (long)n * HC + coff);
    float4 acc = {0.f, 0.f, 0.f, 0.f};
    float lrun = 0.f;
    int s0 = base[n], end = s0 + deg[n];

    for (int s = s0; s < end; s += B){
      int2 pk[NP]; bool val[NP];
      #pragma unroll
      for (int t = 0; t < NP; t++){
        int idx = s + t * ES + slot;
        val[t] = idx < end;
        pk[t]  = csr_pack[val[t] ? idx : s0];
      }
      float4 row[NP];
      #pragma unroll
      for (int t = 0; t < NP; t++)
        row[t] = *(const float4*)(xl + (long)pk[t].x * HC + coff);
      #pragma unroll
      for (int t = 0; t < NP; t++){
        float eav = __int_as_float(pk[t].y);
        float t0 = row[t].x + xrv.x + eav * wev.x;
        float t1 = row[t].y + xrv.y + eav * wev.y;
        float t2 = row[t].z + xrv.z + eav * wev.z;
        float t3 = row[t].w + xrv.w + eav * wev.w;
        float m0 = fmaxf(t0, 0.f) + NEG_SLOPE * fminf(t0, 0.f);
        float m1 = fmaxf(t1, 0.f) + NEG_SLOPE * fminf(t1, 0.f);
        float m2 = fmaxf(t2, 0.f) + NEG_SLOPE * fminf(t2, 0.f);
        float m3 = fmaxf(t3, 0.f) + NEG_SLOPE * fminf(t3, 0.f);
        float p = ((m0 * attv.x + m1 * attv.y) + (m2 * attv.z + m3 * attv.w));
        #pragma unroll
        for (int o = 1; o < LPH; o <<= 1) p += __shfl_xor(p, o);
        float pe = val[t] ? __expf(p) : 0.f;
        lrun  += pe;
        acc.x += pe * row[t].x;
        acc.y += pe * row[t].y;
        acc.z += pe * row[t].z;
        acc.w += pe * row[t].w;
      }
    }
    // reduce over edge slots
    #pragma unroll
    for (int o = LPE; o < 64; o <<= 1){
      lrun  += __shfl_xor(lrun, o);
      acc.x += __shfl_xor(acc.x, o);
      acc.y += __shfl_xor(acc.y, o);
      acc.z += __shfl_xor(acc.z, o);
      acc.w += __shfl_xor(acc.w, o);
    }
    float inv = 1.f / (lrun + 1e-16f);
    float4 o4;
    o4.x = acc.x * inv + bv.x;
    o4.y = acc.y * inv + bv.y;
    o4.z = acc.z * inv + bv.z;
    o4.w = acc.w * inv + bv.w;
    if (do_elu){
      o4.x = o4.x > 0.f ? o4.x : (__expf(o4.x) - 1.f);
      o4.y = o4.y > 0.f ? o4.y : (__expf(o4.y) - 1.f);
      o4.z = o4.z > 0.f ? o4.z : (__expf(o4.z) - 1.f);
      o4.w = o4.w > 0.f ? o4.w : (__expf(o4.w) - 1.f);
    }
    if (outF){
      // fused final linear: out[n] = sum_c o_c * Wlin_c + blin
      float v = ((o4.x * wl.x + o4.y * wl.y) + (o4.z * wl.z + o4.w * wl.w));
      #pragma unroll
      for (int o = 1; o < LPE; o <<= 1) v += __shfl_xor(v, o);
      if (lane == 0) outF[n] = v + blin[0];
    } else if (packH){
      // write MFMA A-fragments: element (kg,row,e) at shorts idx (kg*N+row)*8+e
      // lane hl holds k = hl*4 .. hl*4+3  ->  kg = hl>>1, e0 = (hl&1)*4
      if (slot == 0){
        unsigned short h0 = f2bf(o4.x), h1 = f2bf(o4.y),
                       h2 = f2bf(o4.z), h3 = f2bf(o4.w);
        s16x4 hv = { (short)h0, (short)h1, (short)h2, (short)h3 };
        s16x4 lv = { (short)f2bf(o4.x - bf2f(h0)), (short)f2bf(o4.y - bf2f(h1)),
                     (short)f2bf(o4.z - bf2f(h2)), (short)f2bf(o4.w - bf2f(h3)) };
        long idx = ((long)(hl >> 1) * N + n) * 8 + (hl & 1) * 4;
        *(s16x4*)(packH + idx) = hv;
        *(s16x4*)(packL + idx) = lv;
      }
    } else {
      if (slot == 0)
        *(float4*)(hout + (long)n * HC + coff) = o4;
    }
  }
}

// ----------------------------------------------------------------
extern "C" void kernel_launch(void* const* d_in, const int* in_sizes, int n_in,
                              void* d_out, int out_size, void* d_ws, size_t ws_size,
                              hipStream_t stream)
{
  const float* x  = (const float*)d_in[0];
  const float* ea = (const float*)d_in[1];
  const int*   ei = (const int*)d_in[2];
  const int N = in_sizes[0] / 15;
  const int E = in_sizes[1];

  const float* P[28];
  for (int i = 0; i < 28; i++) P[i] = (const float*)d_in[3 + i];
  const float* Wlin = (const float*)d_in[31];
  const float* blin = (const float*)d_in[32];

  size_t off = 0;
  auto carve = [&](size_t bytes) -> char* {
    char* p = (char*)d_ws + off;
    off = (off + bytes + 255) & ~(size_t)255;
    return p;
  };
  int*   meta     = (int*)  carve(sizeof(int)  * (size_t)(3 * N + 64));
  int*   deg      = meta;                // [N] zeroed
  int*   pos      = meta + N;            // [N] zeroed
  int*   base     = meta + 2 * N;        // [N]
  int*   counter  = meta + 3 * N;        // [1] zeroed
  int2*  csr_pack = (int2*) carve(sizeof(int2) * (size_t)E);
  float* xl       = (float*)carve(sizeof(float) * (size_t)N * 128);
  float* xr       = (float*)carve(sizeof(float) * (size_t)N * 128);
  short* pak_h    = (short*)carve(sizeof(short) * (size_t)N * 128);
  short* pak_l    = (short*)carve(sizeof(short) * (size_t)N * 128);
  // prepacked bf16 hi/lo weights, MFMA B-fragment order
  short* ph1 = (short*)carve(sizeof(short) * 4096);
  short* pl1 = (short*)carve(sizeof(short) * 4096);
  short* ph2 = (short*)carve(sizeof(short) * 32768);
  short* pl2 = (short*)carve(sizeof(short) * 32768);
  short* ph3 = (short*)carve(sizeof(short) * 32768);
  short* pl3 = (short*)carve(sizeof(short) * 32768);
  short* ph4 = (short*)carve(sizeof(short) * 16384);
  short* pl4 = (short*)carve(sizeof(short) * 16384);

  hipMemsetAsync(deg,     0, sizeof(int) * (size_t)(2 * N), stream);
  hipMemsetAsync(counter, 0, sizeof(int), stream);

  int eb = (E + 255) / 256;
  int nb = (N + 255) / 256;
  deg_count_kernel  <<<eb, 256, 0, stream>>>(ei + E, deg, E);
  base_assign_kernel<<<nb, 256, 0, stream>>>(deg, base, counter, N);
  fill_kernel       <<<eb, 256, 0, stream>>>(ei, ea, base, pos, csr_pack, E);
  prep_w_kernel     <<<42, 256, 0, stream>>>(P[0],  P[2],  ph1, pl1,
                                             P[7],  P[9],  ph2, pl2,
                                             P[14], P[16], ph3, pl3,
                                             P[21], P[23], ph4, pl4);

  int gm    = (N + 63) / 64;  // 64-row MFMA tiles
  int agrid = 2048;           // agg: grid-stride, 8 waves/block

  // layer 1: din=15, H*C=128, ELU; agg writes packed A for gemm2
  gemm_dual_mfma<128, 15><<<gm, 256, 0, stream>>>(x, ph1, pl1, P[1], P[3], xl, xr, N);
  agg_kernel<16><<<agrid, 512, 0, stream>>>(xl, xr, base, deg, csr_pack, P[4], P[5], P[6],
                                            nullptr, pak_h, pak_l,
                                            nullptr, nullptr, nullptr, N, 1);
  // layer 2: din=128, ELU; agg writes packed A for gemm3
  gemm_dual_packed<128><<<gm, 256, 0, stream>>>(pak_h, pak_l, ph2, pl2, P[8], P[10], xl, xr, N);
  agg_kernel<16><<<agrid, 512, 0, stream>>>(xl, xr, base, deg, csr_pack, P[11], P[12], P[13],
                                            nullptr, pak_h, pak_l,
                                            nullptr, nullptr, nullptr, N, 1);
  // layer 3: din=128, ELU; agg writes packed A for gemm4
  gemm_dual_packed<128><<<gm, 256, 0, stream>>>(pak_h, pak_l, ph3, pl3, P[15], P[17], xl, xr, N);
  agg_kernel<16><<<agrid, 512, 0, stream>>>(xl, xr, base, deg, csr_pack, P[18], P[19], P[20],
                                            nullptr, pak_h, pak_l,
                                            nullptr, nullptr, nullptr, N, 1);
  // layer 4: din=128, H*C=64, no ELU + fused final linear 64->1
  gemm_dual_packed<64><<<gm, 256, 0, stream>>>(pak_h, pak_l, ph4, pl4, P[22], P[24], xl, xr, N);
  agg_kernel<8><<<agrid, 512, 0, stream>>>(xl, xr, base, deg, csr_pack, P[25], P[26], P[27],
                                           nullptr, nullptr, nullptr,
                                           Wlin, blin, (float*)d_out, N, 0);
}

// Round 5
// 516.126 us; speedup vs baseline: 1.1198x; 1.0355x over previous
//
#include <hip/hip_runtime.h>
#include <math.h>

#define NEG_SLOPE 0.2f

typedef short s16x4 __attribute__((ext_vector_type(4)));
typedef short s16x8 __attribute__((ext_vector_type(8)));
typedef float f32x16 __attribute__((ext_vector_type(16)));
typedef _Float16 f16x4 __attribute__((ext_vector_type(4)));

// float -> bf16 (round-to-nearest-even), and back
__device__ __forceinline__ unsigned short f2bf(float x){
  unsigned int u = __float_as_uint(x);
  unsigned int r = u + 0x7FFFu + ((u >> 16) & 1u);
  return (unsigned short)(r >> 16);
}
__device__ __forceinline__ float bf2f(unsigned short h){
  return __uint_as_float(((unsigned int)h) << 16);
}

// ---------------------------------------------------------------- CSR build
__global__ void deg_count_kernel(const int* __restrict__ dst, int* __restrict__ deg, int E){
  int e = blockIdx.x * blockDim.x + threadIdx.x;
  if (e < E) atomicAdd(&deg[dst[e]], 1);
}

// R5: block-scan prefix allocation (196 atomics total) instead of 50k
// same-address atomics (serialized at L2).
__global__ __launch_bounds__(256) void base_assign_kernel(
    const int* __restrict__ deg, int* __restrict__ base,
    int* __restrict__ counter, int N){
  __shared__ int wsum[4];
  __shared__ int bbase;
  int n = blockIdx.x * 256 + threadIdx.x;
  int d = (n < N) ? deg[n] : 0;
  int lane = threadIdx.x & 63;
  int wid  = threadIdx.x >> 6;
  int scan = d;
  #pragma unroll
  for (int o = 1; o < 64; o <<= 1){
    int t = __shfl_up(scan, o);
    if (lane >= o) scan += t;
  }
  if (lane == 63) wsum[wid] = scan;
  __syncthreads();
  if (threadIdx.x == 0){
    int tot = 0;
    #pragma unroll
    for (int i = 0; i < 4; i++){ int w = wsum[i]; wsum[i] = tot; tot += w; }
    bbase = atomicAdd(counter, tot);
  }
  __syncthreads();
  if (n < N) base[n] = bbase + wsum[wid] + scan - d;
}

__global__ void fill_kernel(const int* __restrict__ ei, const float* __restrict__ ea,
                            const int* __restrict__ base, int* __restrict__ pos,
                            int2* __restrict__ csr_pack, int E){
  int e = blockIdx.x * blockDim.x + threadIdx.x;
  if (e >= E) return;
  int s = ei[e], d = ei[E + e];
  int p = atomicAdd(&pos[d], 1);
  csr_pack[base[d] + p] = make_int2(s, __float_as_int(ea[e]));
}

// ---------------------------------------------------------------- weight prep
// Pack W1|W2 (each [K][NOUT] fp32 row-major) into bf16 hi/lo arrays laid out as
// [kgroup][col(2*NOUT)][8 k-elems] -- exactly the MFMA B-fragment order, so the
// GEMM reads B fragments as fully-coalesced 16B-per-lane global loads.
__device__ __forceinline__ void pack_pair(const float* __restrict__ W1,
                                          const float* __restrict__ W2,
                                          short* __restrict__ H, short* __restrict__ L,
                                          int id, int K, int NOUT){
  int BN = 2 * NOUT;
  int kg = id / BN, cb = id - kg * BN;
  const float* W = (cb < NOUT) ? W1 : W2;
  int c = (cb < NOUT) ? cb : cb - NOUT;
  s16x8 hv, lv;
  #pragma unroll
  for (int e = 0; e < 8; e++){
    int k = kg * 8 + e;
    float v = (k < K) ? W[(long)k * NOUT + c] : 0.f;
    unsigned short h = f2bf(v);
    hv[e] = (short)h;
    lv[e] = (short)f2bf(v - bf2f(h));
  }
  *(s16x8*)&H[(long)id * 8] = hv;
  *(s16x8*)&L[(long)id * 8] = lv;
}

__global__ void prep_w_kernel(const float* Wl1, const float* Wr1, short* H1, short* L1,
                              const float* Wl2, const float* Wr2, short* H2, short* L2,
                              const float* Wl3, const float* Wr3, short* H3, short* L3,
                              const float* Wl4, const float* Wr4, short* H4, short* L4){
  int id = blockIdx.x * blockDim.x + threadIdx.x;
  if (id < 512)  { pack_pair(Wl1, Wr1, H1, L1, id, 15, 128); return; }   // KG=2,  BN=256
  id -= 512;
  if (id < 4096) { pack_pair(Wl2, Wr2, H2, L2, id, 128, 128); return; }  // KG=16, BN=256
  id -= 4096;
  if (id < 4096) { pack_pair(Wl3, Wr3, H3, L3, id, 128, 128); return; }
  id -= 4096;
  if (id < 2048) { pack_pair(Wl4, Wr4, H4, L4, id, 128, 64); return; }   // KG=16, BN=128
}

// ---------------------------------------------------------------- MFMA dual GEMM (layer 1, K=15)
// A gathered+converted in-kernel (cheap at K=15: 1 kstep). Outputs fp16 (R5):
// xl/xr are only consumed by the agg (attention values); precision path to the
// next gemm flows through the agg's bf16 hi/lo pack, not these.
// Fragment layouts (gfx950 v_mfma_f32_32x32x16_bf16):
//   A: row = lane&31, k = 8*(lane>>5)+e     B: col = lane&31, k = 8*(lane>>5)+e
//   D: col = lane&31, row = (reg&3) + 8*(reg>>2) + 4*(lane>>5)
template<int NOUT, int K>
__global__ __launch_bounds__(256) void gemm_dual_mfma(
    const float* __restrict__ X,
    const short* __restrict__ BH, const short* __restrict__ BL,
    const float* __restrict__ b1, const float* __restrict__ b2,
    _Float16* __restrict__ Y1, _Float16* __restrict__ Y2, int N)
{
  constexpr int BN     = 2 * NOUT;
  constexpr int KSTEPS = (K + 15) / 16;     // one 32x32x16 MFMA step each
  constexpr int NR     = NOUT / 32;         // col fragments per wave (4 or 2)

  int tid   = threadIdx.x;
  int lane  = tid & 63;
  int wid   = tid >> 6;
  int wm    = wid >> 1, wn = wid & 1;       // block = 64 rows x (Y1|Y2)
  int llane = lane & 31, hlane = lane >> 5;
  int r0    = blockIdx.x * 64;

  // ---- A: load this lane's row (half-K per lane-half), convert hi/lo once
  int arow  = r0 + wm * 32 + llane;
  bool rv   = arow < N;
  const float* px = X + (long)arow * K;

  s16x8 ah[KSTEPS], al[KSTEPS];
  #pragma unroll
  for (int ks = 0; ks < KSTEPS; ks++){
    int kg = (2 * ks + hlane) * 8;
    float v[8];
    if constexpr (K % 8 == 0){
      float4 p0 = {0.f,0.f,0.f,0.f}, p1 = {0.f,0.f,0.f,0.f};
      if (rv){
        p0 = *(const float4*)(px + kg);
        p1 = *(const float4*)(px + kg + 4);
      }
      v[0]=p0.x; v[1]=p0.y; v[2]=p0.z; v[3]=p0.w;
      v[4]=p1.x; v[5]=p1.y; v[6]=p1.z; v[7]=p1.w;
    } else {
      #pragma unroll
      for (int e = 0; e < 8; e++)
        v[e] = (rv && kg + e < K) ? px[kg + e] : 0.f;
    }
    #pragma unroll
    for (int e = 0; e < 8; e++){
      unsigned short h = f2bf(v[e]);
      ah[ks][e] = (short)h;
      al[ks][e] = (short)f2bf(v[e] - bf2f(h));
    }
  }

  f32x16 acc[NR];
  #pragma unroll
  for (int n = 0; n < NR; n++)
    #pragma unroll
    for (int i = 0; i < 16; i++) acc[n][i] = 0.f;

  const s16x8* BHf = (const s16x8*)BH;
  const s16x8* BLf = (const s16x8*)BL;
  #pragma unroll
  for (int ks = 0; ks < KSTEPS; ks++){
    long fb = (long)(2 * ks + hlane) * BN + wn * NOUT + llane;
    s16x8 bh[NR], bl[NR];
    #pragma unroll
    for (int n = 0; n < NR; n++){
      bh[n] = BHf[fb + n * 32];
      bl[n] = BLf[fb + n * 32];
    }
    #pragma unroll
    for (int n = 0; n < NR; n++)
      acc[n] = __builtin_amdgcn_mfma_f32_32x32x16_bf16(ah[ks], bh[n], acc[n], 0, 0, 0);
    #pragma unroll
    for (int n = 0; n < NR; n++)
      acc[n] = __builtin_amdgcn_mfma_f32_32x32x16_bf16(ah[ks], bl[n], acc[n], 0, 0, 0);
    #pragma unroll
    for (int n = 0; n < NR; n++)
      acc[n] = __builtin_amdgcn_mfma_f32_32x32x16_bf16(al[ks], bh[n], acc[n], 0, 0, 0);
  }

  const float* bsrc = wn ? b2 : b1;
  _Float16* Y = wn ? Y2 : Y1;
  #pragma unroll
  for (int n = 0; n < NR; n++){
    float bias = bsrc[n * 32 + llane];
    #pragma unroll
    for (int reg = 0; reg < 16; reg++){
      int row = r0 + wm * 32 + (reg & 3) + 8 * (reg >> 2) + 4 * hlane;
      if (row < N)
        Y[(long)row * NOUT + n * 32 + llane] = (_Float16)(acc[n][reg] + bias);
    }
  }
}

// ---------------------------------------------------------------- packed-A MFMA dual GEMM (K=128)
// A comes prepacked in fragment order [kgroup][row][8k] (bf16 hi/lo), written by
// the previous layer's agg epilogue. Both operands are fully-coalesced 16B/lane
// streams; no LDS, no barriers, no in-kernel convert. fp16 outputs (R5).
template<int NOUT>
__global__ __launch_bounds__(256) void gemm_dual_packed(
    const short* __restrict__ AH, const short* __restrict__ AL,
    const short* __restrict__ BH, const short* __restrict__ BL,
    const float* __restrict__ b1, const float* __restrict__ b2,
    _Float16* __restrict__ Y1, _Float16* __restrict__ Y2, int N)
{
  constexpr int BN     = 2 * NOUT;
  constexpr int KSTEPS = 8;                 // K = 128
  constexpr int NR     = NOUT / 32;

  int tid   = threadIdx.x;
  int lane  = tid & 63;
  int wid   = tid >> 6;
  int wm    = wid >> 1, wn = wid & 1;
  int llane = lane & 31, hlane = lane >> 5;
  int r0    = blockIdx.x * 64;
  int arow  = r0 + wm * 32 + llane;
  int ar    = arow < N ? arow : N - 1;      // clamp: extra rows never stored

  const s16x8* AHf = (const s16x8*)AH;
  const s16x8* ALf = (const s16x8*)AL;
  const s16x8* BHf = (const s16x8*)BH;
  const s16x8* BLf = (const s16x8*)BL;

  f32x16 acc[NR];
  #pragma unroll
  for (int n = 0; n < NR; n++)
    #pragma unroll
    for (int i = 0; i < 16; i++) acc[n][i] = 0.f;

  #pragma unroll
  for (int ks = 0; ks < KSTEPS; ks++){
    long fa = (long)(2 * ks + hlane) * N + ar;
    s16x8 ah = AHf[fa];
    s16x8 al = ALf[fa];
    long fb = (long)(2 * ks + hlane) * BN + wn * NOUT + llane;
    s16x8 bh[NR], bl[NR];
    #pragma unroll
    for (int n = 0; n < NR; n++){
      bh[n] = BHf[fb + n * 32];
      bl[n] = BLf[fb + n * 32];
    }
    #pragma unroll
    for (int n = 0; n < NR; n++)
      acc[n] = __builtin_amdgcn_mfma_f32_32x32x16_bf16(ah, bh[n], acc[n], 0, 0, 0);
    #pragma unroll
    for (int n = 0; n < NR; n++)
      acc[n] = __builtin_amdgcn_mfma_f32_32x32x16_bf16(ah, bl[n], acc[n], 0, 0, 0);
    #pragma unroll
    for (int n = 0; n < NR; n++)
      acc[n] = __builtin_amdgcn_mfma_f32_32x32x16_bf16(al, bh[n], acc[n], 0, 0, 0);
  }

  const float* bsrc = wn ? b2 : b1;
  _Float16* Y = wn ? Y2 : Y1;
  #pragma unroll
  for (int n = 0; n < NR; n++){
    float bias = bsrc[n * 32 + llane];
    #pragma unroll
    for (int reg = 0; reg < 16; reg++){
      int row = r0 + wm * 32 + (reg & 3) + 8 * (reg >> 2) + 4 * hlane;
      if (row < N)
        Y[(long)row * NOUT + n * 32 + llane] = (_Float16)(acc[n][reg] + bias);
    }
  }
}

// ---------------------------------------------------------------- fused edge softmax + aggregation
// One wave per dst node (grid-stride). Lane = (edge-slot, head, channel-quad).
// R5: xl/xr are fp16 (halves the random-gather byte stream: 256B/row for C=16;
// working set 12.8MB -> better L2 hit rate). Accumulation stays fp32; the
// precision path to the next gemm is the bf16 hi/lo pack of the fp32 result.
// NOTE (R1 post-mortem): do NOT predicate the NP loads on tail occupancy --
// it broke 8-deep load batching and cost +50%.
template<int C>
__global__ __launch_bounds__(512) void agg_kernel(
    const _Float16* __restrict__ xl, const _Float16* __restrict__ xr,
    const int* __restrict__ base, const int* __restrict__ deg,
    const int2* __restrict__ csr_pack,
    const float* __restrict__ We, const float* __restrict__ att,
    const float* __restrict__ bias, float* __restrict__ hout,
    short* __restrict__ packH, short* __restrict__ packL,
    const float* __restrict__ Wlin, const float* __restrict__ blin,
    float* __restrict__ outF, int N, int do_elu)
{
  constexpr int HC  = 8 * C;
  constexpr int LPH = C / 4;       // lanes per head
  constexpr int LPE = 8 * LPH;     // lanes per edge (32 or 16)
  constexpr int ES  = 64 / LPE;    // edge slots per pass (2 or 4)
  constexpr int NP  = 4;           // passes per iteration
  constexpr int B   = ES * NP;     // edges per iteration (8 or 16)

  int lane = threadIdx.x & 63;
  int wv   = blockIdx.x * (blockDim.x >> 6) + (threadIdx.x >> 6);
  int nwv  = gridDim.x * (blockDim.x >> 6);
  int slot = lane / LPE;           // edge slot within pass
  int hl   = lane % LPE;           // position within edge
  int coff = hl * 4;               // channel offset: h*C + g*4 == hl*4

  float4 attv = *(const float4*)(att  + coff);
  float4 wev  = *(const float4*)(We   + coff);
  float4 bv   = *(const float4*)(bias + coff);
  float4 wl   = outF ? *(const float4*)(Wlin + coff) : make_float4(0.f,0.f,0.f,0.f);

  for (int n = wv; n < N; n += nwv){
    f16x4 xrh = *(const f16x4*)(xr + (long)n * HC + coff);
    float4 xrv = make_float4((float)xrh[0], (float)xrh[1], (float)xrh[2], (float)xrh[3]);
    float4 acc = {0.f, 0.f, 0.f, 0.f};
    float lrun = 0.f;
    int s0 = base[n], end = s0 + deg[n];

    for (int s = s0; s < end; s += B){
      int2 pk[NP]; bool val[NP];
      #pragma unroll
      for (int t = 0; t < NP; t++){
        int idx = s + t * ES + slot;
        val[t] = idx < end;
        pk[t]  = csr_pack[val[t] ? idx : s0];
      }
      f16x4 rh[NP];
      #pragma unroll
      for (int t = 0; t < NP; t++)
        rh[t] = *(const f16x4*)(xl + (long)pk[t].x * HC + coff);
      #pragma unroll
      for (int t = 0; t < NP; t++){
        float4 row = make_float4((float)rh[t][0], (float)rh[t][1],
                                 (float)rh[t][2], (float)rh[t][3]);
        float eav = __int_as_float(pk[t].y);
        float t0 = row.x + xrv.x + eav * wev.x;
        float t1 = row.y + xrv.y + eav * wev.y;
        float t2 = row.z + xrv.z + eav * wev.z;
        float t3 = row.w + xrv.w + eav * wev.w;
        float m0 = fmaxf(t0, 0.f) + NEG_SLOPE * fminf(t0, 0.f);
        float m1 = fmaxf(t1, 0.f) + NEG_SLOPE * fminf(t1, 0.f);
        float m2 = fmaxf(t2, 0.f) + NEG_SLOPE * fminf(t2, 0.f);
        float m3 = fmaxf(t3, 0.f) + NEG_SLOPE * fminf(t3, 0.f);
        float p = ((m0 * attv.x + m1 * attv.y) + (m2 * attv.z + m3 * attv.w));
        #pragma unroll
        for (int o = 1; o < LPH; o <<= 1) p += __shfl_xor(p, o);
        float pe = val[t] ? __expf(p) : 0.f;
        lrun  += pe;
        acc.x += pe * row.x;
        acc.y += pe * row.y;
        acc.z += pe * row.z;
        acc.w += pe * row.w;
      }
    }
    // reduce over edge slots
    #pragma unroll
    for (int o = LPE; o < 64; o <<= 1){
      lrun  += __shfl_xor(lrun, o);
      acc.x += __shfl_xor(acc.x, o);
      acc.y += __shfl_xor(acc.y, o);
      acc.z += __shfl_xor(acc.z, o);
      acc.w += __shfl_xor(acc.w, o);
    }
    float inv = 1.f / (lrun + 1e-16f);
    float4 o4;
    o4.x = acc.x * inv + bv.x;
    o4.y = acc.y * inv + bv.y;
    o4.z = acc.z * inv + bv.z;
    o4.w = acc.w * inv + bv.w;
    if (do_elu){
      o4.x = o4.x > 0.f ? o4.x : (__expf(o4.x) - 1.f);
      o4.y = o4.y > 0.f ? o4.y : (__expf(o4.y) - 1.f);
      o4.z = o4.z > 0.f ? o4.z : (__expf(o4.z) - 1.f);
      o4.w = o4.w > 0.f ? o4.w : (__expf(o4.w) - 1.f);
    }
    if (outF){
      // fused final linear: out[n] = sum_c o_c * Wlin_c + blin
      float v = ((o4.x * wl.x + o4.y * wl.y) + (o4.z * wl.z + o4.w * wl.w));
      #pragma unroll
      for (int o = 1; o < LPE; o <<= 1) v += __shfl_xor(v, o);
      if (lane == 0) outF[n] = v + blin[0];
    } else if (packH){
      // write MFMA A-fragments: element (kg,row,e) at shorts idx (kg*N+row)*8+e
      // lane hl holds k = hl*4 .. hl*4+3  ->  kg = hl>>1, e0 = (hl&1)*4
      if (slot == 0){
        unsigned short h0 = f2bf(o4.x), h1 = f2bf(o4.y),
                       h2 = f2bf(o4.z), h3 = f2bf(o4.w);
        s16x4 hv = { (short)h0, (short)h1, (short)h2, (short)h3 };
        s16x4 lv = { (short)f2bf(o4.x - bf2f(h0)), (short)f2bf(o4.y - bf2f(h1)),
                     (short)f2bf(o4.z - bf2f(h2)), (short)f2bf(o4.w - bf2f(h3)) };
        long idx = ((long)(hl >> 1) * N + n) * 8 + (hl & 1) * 4;
        *(s16x4*)(packH + idx) = hv;
        *(s16x4*)(packL + idx) = lv;
      }
    } else {
      if (slot == 0)
        *(float4*)(hout + (long)n * HC + coff) = o4;
    }
  }
}

// ----------------------------------------------------------------
extern "C" void kernel_launch(void* const* d_in, const int* in_sizes, int n_in,
                              void* d_out, int out_size, void* d_ws, size_t ws_size,
                              hipStream_t stream)
{
  const float* x  = (const float*)d_in[0];
  const float* ea = (const float*)d_in[1];
  const int*   ei = (const int*)d_in[2];
  const int N = in_sizes[0] / 15;
  const int E = in_sizes[1];

  const float* P[28];
  for (int i = 0; i < 28; i++) P[i] = (const float*)d_in[3 + i];
  const float* Wlin = (const float*)d_in[31];
  const float* blin = (const float*)d_in[32];

  size_t off = 0;
  auto carve = [&](size_t bytes) -> char* {
    char* p = (char*)d_ws + off;
    off = (off + bytes + 255) & ~(size_t)255;
    return p;
  };
  int*   meta     = (int*)  carve(sizeof(int)  * (size_t)(3 * N + 64));
  int*   deg      = meta;                // [N] zeroed
  int*   pos      = meta + N;            // [N] zeroed
  int*   base     = meta + 2 * N;        // [N]
  int*   counter  = meta + 3 * N;        // [1] zeroed
  int2*  csr_pack = (int2*) carve(sizeof(int2) * (size_t)E);
  _Float16* xl    = (_Float16*)carve(sizeof(_Float16) * (size_t)N * 128);
  _Float16* xr    = (_Float16*)carve(sizeof(_Float16) * (size_t)N * 128);
  short* pak_h    = (short*)carve(sizeof(short) * (size_t)N * 128);
  short* pak_l    = (short*)carve(sizeof(short) * (size_t)N * 128);
  // prepacked bf16 hi/lo weights, MFMA B-fragment order
  short* ph1 = (short*)carve(sizeof(short) * 4096);
  short* pl1 = (short*)carve(sizeof(short) * 4096);
  short* ph2 = (short*)carve(sizeof(short) * 32768);
  short* pl2 = (short*)carve(sizeof(short) * 32768);
  short* ph3 = (short*)carve(sizeof(short) * 32768);
  short* pl3 = (short*)carve(sizeof(short) * 32768);
  short* ph4 = (short*)carve(sizeof(short) * 16384);
  short* pl4 = (short*)carve(sizeof(short) * 16384);

  hipMemsetAsync(deg,     0, sizeof(int) * (size_t)(2 * N), stream);
  hipMemsetAsync(counter, 0, sizeof(int), stream);

  int eb = (E + 255) / 256;
  int nb = (N + 255) / 256;
  deg_count_kernel  <<<eb, 256, 0, stream>>>(ei + E, deg, E);
  base_assign_kernel<<<nb, 256, 0, stream>>>(deg, base, counter, N);
  fill_kernel       <<<eb, 256, 0, stream>>>(ei, ea, base, pos, csr_pack, E);
  prep_w_kernel     <<<42, 256, 0, stream>>>(P[0],  P[2],  ph1, pl1,
                                             P[7],  P[9],  ph2, pl2,
                                             P[14], P[16], ph3, pl3,
                                             P[21], P[23], ph4, pl4);

  int gm    = (N + 63) / 64;  // 64-row MFMA tiles
  int agrid = 2048;           // agg: grid-stride, 8 waves/block

  // layer 1: din=15, H*C=128, ELU; agg writes packed A for gemm2
  gemm_dual_mfma<128, 15><<<gm, 256, 0, stream>>>(x, ph1, pl1, P[1], P[3], xl, xr, N);
  agg_kernel<16><<<agrid, 512, 0, stream>>>(xl, xr, base, deg, csr_pack, P[4], P[5], P[6],
                                            nullptr, pak_h, pak_l,
                                            nullptr, nullptr, nullptr, N, 1);
  // layer 2: din=128, ELU; agg writes packed A for gemm3
  gemm_dual_packed<128><<<gm, 256, 0, stream>>>(pak_h, pak_l, ph2, pl2, P[8], P[10], xl, xr, N);
  agg_kernel<16><<<agrid, 512, 0, stream>>>(xl, xr, base, deg, csr_pack, P[11], P[12], P[13],
                                            nullptr, pak_h, pak_l,
                                            nullptr, nullptr, nullptr, N, 1);
  // layer 3: din=128, ELU; agg writes packed A for gemm4
  gemm_dual_packed<128><<<gm, 256, 0, stream>>>(pak_h, pak_l, ph3, pl3, P[15], P[17], xl, xr, N);
  agg_kernel<16><<<agrid, 512, 0, stream>>>(xl, xr, base, deg, csr_pack, P[18], P[19], P[20],
                                            nullptr, pak_h, pak_l,
                                            nullptr, nullptr, nullptr, N, 1);
  // layer 4: din=128, H*C=64, no ELU + fused final linear 64->1
  gemm_dual_packed<64><<<gm, 256, 0, stream>>>(pak_h, pak_l, ph4, pl4, P[22], P[24], xl, xr, N);
  agg_kernel<8><<<agrid, 512, 0, stream>>>(xl, xr, base, deg, csr_pack, P[25], P[26], P[27],
                                           nullptr, nullptr, nullptr,
                                           Wlin, blin, (float*)d_out, N, 0);
}

// Round 6
// 479.913 us; speedup vs baseline: 1.2043x; 1.0755x over previous
//
#include <hip/hip_runtime.h>
#include <math.h>

#define NEG_SLOPE 0.2f

typedef short s16x4 __attribute__((ext_vector_type(4)));
typedef short s16x8 __attribute__((ext_vector_type(8)));
typedef float f32x16 __attribute__((ext_vector_type(16)));
typedef _Float16 f16x2 __attribute__((ext_vector_type(2)));
typedef _Float16 f16x4 __attribute__((ext_vector_type(4)));

// float -> bf16 (round-to-nearest-even), and back
__device__ __forceinline__ unsigned short f2bf(float x){
  unsigned int u = __float_as_uint(x);
  unsigned int r = u + 0x7FFFu + ((u >> 16) & 1u);
  return (unsigned short)(r >> 16);
}
__device__ __forceinline__ float bf2f(unsigned short h){
  return __uint_as_float(((unsigned int)h) << 16);
}

// ---------------------------------------------------------------- CSR build
__global__ void deg_count_kernel(const int* __restrict__ dst, int* __restrict__ deg, int E){
  int e = blockIdx.x * blockDim.x + threadIdx.x;
  if (e < E) atomicAdd(&deg[dst[e]], 1);
}

// R5: block-scan prefix allocation (196 atomics total) instead of 50k
// same-address atomics (serialized at L2).
__global__ __launch_bounds__(256) void base_assign_kernel(
    const int* __restrict__ deg, int* __restrict__ base,
    int* __restrict__ counter, int N){
  __shared__ int wsum[4];
  __shared__ int bbase;
  int n = blockIdx.x * 256 + threadIdx.x;
  int d = (n < N) ? deg[n] : 0;
  int lane = threadIdx.x & 63;
  int wid  = threadIdx.x >> 6;
  int scan = d;
  #pragma unroll
  for (int o = 1; o < 64; o <<= 1){
    int t = __shfl_up(scan, o);
    if (lane >= o) scan += t;
  }
  if (lane == 63) wsum[wid] = scan;
  __syncthreads();
  if (threadIdx.x == 0){
    int tot = 0;
    #pragma unroll
    for (int i = 0; i < 4; i++){ int w = wsum[i]; wsum[i] = tot; tot += w; }
    bbase = atomicAdd(counter, tot);
  }
  __syncthreads();
  if (n < N) base[n] = bbase + wsum[wid] + scan - d;
}

// R6: ea stored as broadcast half2 bits (h | h<<16) -- the agg reads it as
// f16x2 with zero per-edge conversion cost.
__global__ void fill_kernel(const int* __restrict__ ei, const float* __restrict__ ea,
                            const int* __restrict__ base, int* __restrict__ pos,
                            int2* __restrict__ csr_pack, int E){
  int e = blockIdx.x * blockDim.x + threadIdx.x;
  if (e >= E) return;
  int s = ei[e], d = ei[E + e];
  int p = atomicAdd(&pos[d], 1);
  _Float16 h = (_Float16)ea[e];
  unsigned int hb = (unsigned int)*(unsigned short*)&h;
  csr_pack[base[d] + p] = make_int2(s, (int)(hb | (hb << 16)));
}

// ---------------------------------------------------------------- weight prep
// Pack W1|W2 (each [K][NOUT] fp32 row-major) into bf16 hi/lo arrays laid out as
// [kgroup][col(2*NOUT)][8 k-elems] -- exactly the MFMA B-fragment order, so the
// GEMM reads B fragments as fully-coalesced 16B-per-lane global loads.
__device__ __forceinline__ void pack_pair(const float* __restrict__ W1,
                                          const float* __restrict__ W2,
                                          short* __restrict__ H, short* __restrict__ L,
                                          int id, int K, int NOUT){
  int BN = 2 * NOUT;
  int kg = id / BN, cb = id - kg * BN;
  const float* W = (cb < NOUT) ? W1 : W2;
  int c = (cb < NOUT) ? cb : cb - NOUT;
  s16x8 hv, lv;
  #pragma unroll
  for (int e = 0; e < 8; e++){
    int k = kg * 8 + e;
    float v = (k < K) ? W[(long)k * NOUT + c] : 0.f;
    unsigned short h = f2bf(v);
    hv[e] = (short)h;
    lv[e] = (short)f2bf(v - bf2f(h));
  }
  *(s16x8*)&H[(long)id * 8] = hv;
  *(s16x8*)&L[(long)id * 8] = lv;
}

__global__ void prep_w_kernel(const float* Wl1, const float* Wr1, short* H1, short* L1,
                              const float* Wl2, const float* Wr2, short* H2, short* L2,
                              const float* Wl3, const float* Wr3, short* H3, short* L3,
                              const float* Wl4, const float* Wr4, short* H4, short* L4){
  int id = blockIdx.x * blockDim.x + threadIdx.x;
  if (id < 512)  { pack_pair(Wl1, Wr1, H1, L1, id, 15, 128); return; }   // KG=2,  BN=256
  id -= 512;
  if (id < 4096) { pack_pair(Wl2, Wr2, H2, L2, id, 128, 128); return; }  // KG=16, BN=256
  id -= 4096;
  if (id < 4096) { pack_pair(Wl3, Wr3, H3, L3, id, 128, 128); return; }
  id -= 4096;
  if (id < 2048) { pack_pair(Wl4, Wr4, H4, L4, id, 128, 64); return; }   // KG=16, BN=128
}

// ---------------------------------------------------------------- MFMA dual GEMM (layer 1, K=15)
// A gathered+converted in-kernel (cheap at K=15: 1 kstep). Outputs fp16:
// xl/xr are only consumed by the agg (attention values); precision path to the
// next gemm flows through the agg's bf16 hi/lo pack, not these.
// Fragment layouts (gfx950 v_mfma_f32_32x32x16_bf16):
//   A: row = lane&31, k = 8*(lane>>5)+e     B: col = lane&31, k = 8*(lane>>5)+e
//   D: col = lane&31, row = (reg&3) + 8*(reg>>2) + 4*(lane>>5)
template<int NOUT, int K>
__global__ __launch_bounds__(256) void gemm_dual_mfma(
    const float* __restrict__ X,
    const short* __restrict__ BH, const short* __restrict__ BL,
    const float* __restrict__ b1, const float* __restrict__ b2,
    _Float16* __restrict__ Y1, _Float16* __restrict__ Y2, int N)
{
  constexpr int BN     = 2 * NOUT;
  constexpr int KSTEPS = (K + 15) / 16;     // one 32x32x16 MFMA step each
  constexpr int NR     = NOUT / 32;         // col fragments per wave (4 or 2)

  int tid   = threadIdx.x;
  int lane  = tid & 63;
  int wid   = tid >> 6;
  int wm    = wid >> 1, wn = wid & 1;       // block = 64 rows x (Y1|Y2)
  int llane = lane & 31, hlane = lane >> 5;
  int r0    = blockIdx.x * 64;

  // ---- A: load this lane's row (half-K per lane-half), convert hi/lo once
  int arow  = r0 + wm * 32 + llane;
  bool rv   = arow < N;
  const float* px = X + (long)arow * K;

  s16x8 ah[KSTEPS], al[KSTEPS];
  #pragma unroll
  for (int ks = 0; ks < KSTEPS; ks++){
    int kg = (2 * ks + hlane) * 8;
    float v[8];
    if constexpr (K % 8 == 0){
      float4 p0 = {0.f,0.f,0.f,0.f}, p1 = {0.f,0.f,0.f,0.f};
      if (rv){
        p0 = *(const float4*)(px + kg);
        p1 = *(const float4*)(px + kg + 4);
      }
      v[0]=p0.x; v[1]=p0.y; v[2]=p0.z; v[3]=p0.w;
      v[4]=p1.x; v[5]=p1.y; v[6]=p1.z; v[7]=p1.w;
    } else {
      #pragma unroll
      for (int e = 0; e < 8; e++)
        v[e] = (rv && kg + e < K) ? px[kg + e] : 0.f;
    }
    #pragma unroll
    for (int e = 0; e < 8; e++){
      unsigned short h = f2bf(v[e]);
      ah[ks][e] = (short)h;
      al[ks][e] = (short)f2bf(v[e] - bf2f(h));
    }
  }

  f32x16 acc[NR];
  #pragma unroll
  for (int n = 0; n < NR; n++)
    #pragma unroll
    for (int i = 0; i < 16; i++) acc[n][i] = 0.f;

  const s16x8* BHf = (const s16x8*)BH;
  const s16x8* BLf = (const s16x8*)BL;
  #pragma unroll
  for (int ks = 0; ks < KSTEPS; ks++){
    long fb = (long)(2 * ks + hlane) * BN + wn * NOUT + llane;
    s16x8 bh[NR], bl[NR];
    #pragma unroll
    for (int n = 0; n < NR; n++){
      bh[n] = BHf[fb + n * 32];
      bl[n] = BLf[fb + n * 32];
    }
    #pragma unroll
    for (int n = 0; n < NR; n++)
      acc[n] = __builtin_amdgcn_mfma_f32_32x32x16_bf16(ah[ks], bh[n], acc[n], 0, 0, 0);
    #pragma unroll
    for (int n = 0; n < NR; n++)
      acc[n] = __builtin_amdgcn_mfma_f32_32x32x16_bf16(ah[ks], bl[n], acc[n], 0, 0, 0);
    #pragma unroll
    for (int n = 0; n < NR; n++)
      acc[n] = __builtin_amdgcn_mfma_f32_32x32x16_bf16(al[ks], bh[n], acc[n], 0, 0, 0);
  }

  const float* bsrc = wn ? b2 : b1;
  _Float16* Y = wn ? Y2 : Y1;
  #pragma unroll
  for (int n = 0; n < NR; n++){
    float bias = bsrc[n * 32 + llane];
    #pragma unroll
    for (int reg = 0; reg < 16; reg++){
      int row = r0 + wm * 32 + (reg & 3) + 8 * (reg >> 2) + 4 * hlane;
      if (row < N)
        Y[(long)row * NOUT + n * 32 + llane] = (_Float16)(acc[n][reg] + bias);
    }
  }
}

// ---------------------------------------------------------------- packed-A MFMA dual GEMM (K=128)
// A comes prepacked in fragment order [kgroup][row][8k] (bf16 hi/lo), written by
// the previous layer's agg epilogue. Both operands are fully-coalesced 16B/lane
// streams; no LDS, no barriers, no in-kernel convert. fp16 outputs.
template<int NOUT>
__global__ __launch_bounds__(256) void gemm_dual_packed(
    const short* __restrict__ AH, const short* __restrict__ AL,
    const short* __restrict__ BH, const short* __restrict__ BL,
    const float* __restrict__ b1, const float* __restrict__ b2,
    _Float16* __restrict__ Y1, _Float16* __restrict__ Y2, int N)
{
  constexpr int BN     = 2 * NOUT;
  constexpr int KSTEPS = 8;                 // K = 128
  constexpr int NR     = NOUT / 32;

  int tid   = threadIdx.x;
  int lane  = tid & 63;
  int wid   = tid >> 6;
  int wm    = wid >> 1, wn = wid & 1;
  int llane = lane & 31, hlane = lane >> 5;
  int r0    = blockIdx.x * 64;
  int arow  = r0 + wm * 32 + llane;
  int ar    = arow < N ? arow : N - 1;      // clamp: extra rows never stored

  const s16x8* AHf = (const s16x8*)AH;
  const s16x8* ALf = (const s16x8*)AL;
  const s16x8* BHf = (const s16x8*)BH;
  const s16x8* BLf = (const s16x8*)BL;

  f32x16 acc[NR];
  #pragma unroll
  for (int n = 0; n < NR; n++)
    #pragma unroll
    for (int i = 0; i < 16; i++) acc[n][i] = 0.f;

  #pragma unroll
  for (int ks = 0; ks < KSTEPS; ks++){
    long fa = (long)(2 * ks + hlane) * N + ar;
    s16x8 ah = AHf[fa];
    s16x8 al = ALf[fa];
    long fb = (long)(2 * ks + hlane) * BN + wn * NOUT + llane;
    s16x8 bh[NR], bl[NR];
    #pragma unroll
    for (int n = 0; n < NR; n++){
      bh[n] = BHf[fb + n * 32];
      bl[n] = BLf[fb + n * 32];
    }
    #pragma unroll
    for (int n = 0; n < NR; n++)
      acc[n] = __builtin_amdgcn_mfma_f32_32x32x16_bf16(ah, bh[n], acc[n], 0, 0, 0);
    #pragma unroll
    for (int n = 0; n < NR; n++)
      acc[n] = __builtin_amdgcn_mfma_f32_32x32x16_bf16(ah, bl[n], acc[n], 0, 0, 0);
    #pragma unroll
    for (int n = 0; n < NR; n++)
      acc[n] = __builtin_amdgcn_mfma_f32_32x32x16_bf16(al, bh[n], acc[n], 0, 0, 0);
  }

  const float* bsrc = wn ? b2 : b1;
  _Float16* Y = wn ? Y2 : Y1;
  #pragma unroll
  for (int n = 0; n < NR; n++){
    float bias = bsrc[n * 32 + llane];
    #pragma unroll
    for (int reg = 0; reg < 16; reg++){
      int row = r0 + wm * 32 + (reg & 3) + 8 * (reg >> 2) + 4 * hlane;
      if (row < N)
        Y[(long)row * NOUT + n * 32 + llane] = (_Float16)(acc[n][reg] + bias);
    }
  }
}

// ---------------------------------------------------------------- fused edge softmax + aggregation
// One wave per dst node (grid-stride). Lane = (edge-slot, head, channel-quad).
// R6: agg is VALU-issue-bound (R5: FETCH halved 190->87MB, dur unchanged,
// VALUBusy 61%). Cut VALU insts: packed fp16 logit math (v_pk_fma/v_pk_max +
// v_dot2_f32_f16), leaky as max(t, 0.2t) (== max(t,0)+0.2min(t,0)), ea
// pre-broadcast as half2 in csr. p/exp/acc stay fp32.
// NOTE (R1 post-mortem): do NOT predicate the NP loads on tail occupancy --
// it broke 8-deep load batching and cost +50%.
template<int C>
__global__ __launch_bounds__(512) void agg_kernel(
    const _Float16* __restrict__ xl, const _Float16* __restrict__ xr,
    const int* __restrict__ base, const int* __restrict__ deg,
    const int2* __restrict__ csr_pack,
    const float* __restrict__ We, const float* __restrict__ att,
    const float* __restrict__ bias, float* __restrict__ hout,
    short* __restrict__ packH, short* __restrict__ packL,
    const float* __restrict__ Wlin, const float* __restrict__ blin,
    float* __restrict__ outF, int N, int do_elu)
{
  constexpr int HC  = 8 * C;
  constexpr int LPH = C / 4;       // lanes per head
  constexpr int LPE = 8 * LPH;     // lanes per edge (32 or 16)
  constexpr int ES  = 64 / LPE;    // edge slots per pass (2 or 4)
  constexpr int NP  = 4;           // passes per iteration
  constexpr int B   = ES * NP;     // edges per iteration (8 or 16)

  int lane = threadIdx.x & 63;
  int wv   = blockIdx.x * (blockDim.x >> 6) + (threadIdx.x >> 6);
  int nwv  = gridDim.x * (blockDim.x >> 6);
  int slot = lane / LPE;           // edge slot within pass
  int hl   = lane % LPE;           // position within edge
  int coff = hl * 4;               // channel offset: h*C + g*4 == hl*4

  float4 attf = *(const float4*)(att  + coff);
  float4 wevf = *(const float4*)(We   + coff);
  float4 bv   = *(const float4*)(bias + coff);
  float4 wl   = outF ? *(const float4*)(Wlin + coff) : make_float4(0.f,0.f,0.f,0.f);

  f16x2 a01 = { (_Float16)attf.x, (_Float16)attf.y };
  f16x2 a23 = { (_Float16)attf.z, (_Float16)attf.w };
  f16x2 w01 = { (_Float16)wevf.x, (_Float16)wevf.y };
  f16x2 w23 = { (_Float16)wevf.z, (_Float16)wevf.w };
  f16x2 sl2 = { (_Float16)NEG_SLOPE, (_Float16)NEG_SLOPE };

  for (int n = wv; n < N; n += nwv){
    f16x4 xr4 = *(const f16x4*)(xr + (long)n * HC + coff);
    f16x2 x01 = __builtin_shufflevector(xr4, xr4, 0, 1);
    f16x2 x23 = __builtin_shufflevector(xr4, xr4, 2, 3);
    float4 acc = {0.f, 0.f, 0.f, 0.f};
    float lrun = 0.f;
    int s0 = base[n], end = s0 + deg[n];

    for (int s = s0; s < end; s += B){
      int2 pk[NP]; bool val[NP];
      #pragma unroll
      for (int t = 0; t < NP; t++){
        int idx = s + t * ES + slot;
        val[t] = idx < end;
        pk[t]  = csr_pack[val[t] ? idx : s0];
      }
      f16x4 rh[NP];
      #pragma unroll
      for (int t = 0; t < NP; t++)
        rh[t] = *(const f16x4*)(xl + (long)pk[t].x * HC + coff);
      #pragma unroll
      for (int t = 0; t < NP; t++){
        f16x2 r01 = __builtin_shufflevector(rh[t], rh[t], 0, 1);
        f16x2 r23 = __builtin_shufflevector(rh[t], rh[t], 2, 3);
        f16x2 ev  = *(const f16x2*)&pk[t].y;      // broadcast half2
        f16x2 t01 = r01 + (ev * w01 + x01);
        f16x2 t23 = r23 + (ev * w23 + x23);
        f16x2 m01 = __builtin_elementwise_max(t01, t01 * sl2);
        f16x2 m23 = __builtin_elementwise_max(t23, t23 * sl2);
        float p = __builtin_amdgcn_fdot2(m01, a01,
                  __builtin_amdgcn_fdot2(m23, a23, 0.f, false), false);
        #pragma unroll
        for (int o = 1; o < LPH; o <<= 1) p += __shfl_xor(p, o);
        float pe = val[t] ? __expf(p) : 0.f;
        lrun  += pe;
        acc.x += pe * (float)r01[0];
        acc.y += pe * (float)r01[1];
        acc.z += pe * (float)r23[0];
        acc.w += pe * (float)r23[1];
      }
    }
    // reduce over edge slots
    #pragma unroll
    for (int o = LPE; o < 64; o <<= 1){
      lrun  += __shfl_xor(lrun, o);
      acc.x += __shfl_xor(acc.x, o);
      acc.y += __shfl_xor(acc.y, o);
      acc.z += __shfl_xor(acc.z, o);
      acc.w += __shfl_xor(acc.w, o);
    }
    float inv = 1.f / (lrun + 1e-16f);
    float4 o4;
    o4.x = acc.x * inv + bv.x;
    o4.y = acc.y * inv + bv.y;
    o4.z = acc.z * inv + bv.z;
    o4.w = acc.w * inv + bv.w;
    if (do_elu){
      o4.x = o4.x > 0.f ? o4.x : (__expf(o4.x) - 1.f);
      o4.y = o4.y > 0.f ? o4.y : (__expf(o4.y) - 1.f);
      o4.z = o4.z > 0.f ? o4.z : (__expf(o4.z) - 1.f);
      o4.w = o4.w > 0.f ? o4.w : (__expf(o4.w) - 1.f);
    }
    if (outF){
      // fused final linear: out[n] = sum_c o_c * Wlin_c + blin
      float v = ((o4.x * wl.x + o4.y * wl.y) + (o4.z * wl.z + o4.w * wl.w));
      #pragma unroll
      for (int o = 1; o < LPE; o <<= 1) v += __shfl_xor(v, o);
      if (lane == 0) outF[n] = v + blin[0];
    } else if (packH){
      // write MFMA A-fragments: element (kg,row,e) at shorts idx (kg*N+row)*8+e
      // lane hl holds k = hl*4 .. hl*4+3  ->  kg = hl>>1, e0 = (hl&1)*4
      if (slot == 0){
        unsigned short h0 = f2bf(o4.x), h1 = f2bf(o4.y),
                       h2 = f2bf(o4.z), h3 = f2bf(o4.w);
        s16x4 hv = { (short)h0, (short)h1, (short)h2, (short)h3 };
        s16x4 lv = { (short)f2bf(o4.x - bf2f(h0)), (short)f2bf(o4.y - bf2f(h1)),
                     (short)f2bf(o4.z - bf2f(h2)), (short)f2bf(o4.w - bf2f(h3)) };
        long idx = ((long)(hl >> 1) * N + n) * 8 + (hl & 1) * 4;
        *(s16x4*)(packH + idx) = hv;
        *(s16x4*)(packL + idx) = lv;
      }
    } else {
      if (slot == 0)
        *(float4*)(hout + (long)n * HC + coff) = o4;
    }
  }
}

// ----------------------------------------------------------------
extern "C" void kernel_launch(void* const* d_in, const int* in_sizes, int n_in,
                              void* d_out, int out_size, void* d_ws, size_t ws_size,
                              hipStream_t stream)
{
  const float* x  = (const float*)d_in[0];
  const float* ea = (const float*)d_in[1];
  const int*   ei = (const int*)d_in[2];
  const int N = in_sizes[0] / 15;
  const int E = in_sizes[1];

  const float* P[28];
  for (int i = 0; i < 28; i++) P[i] = (const float*)d_in[3 + i];
  const float* Wlin = (const float*)d_in[31];
  const float* blin = (const float*)d_in[32];

  size_t off = 0;
  auto carve = [&](size_t bytes) -> char* {
    char* p = (char*)d_ws + off;
    off = (off + bytes + 255) & ~(size_t)255;
    return p;
  };
  int*   meta     = (int*)  carve(sizeof(int)  * (size_t)(3 * N + 64));
  int*   deg      = meta;                // [N] zeroed
  int*   pos      = meta + N;            // [N] zeroed
  int*   base     = meta + 2 * N;        // [N]
  int*   counter  = meta + 3 * N;        // [1] zeroed
  int2*  csr_pack = (int2*) carve(sizeof(int2) * (size_t)E);
  _Float16* xl    = (_Float16*)carve(sizeof(_Float16) * (size_t)N * 128);
  _Float16* xr    = (_Float16*)carve(sizeof(_Float16) * (size_t)N * 128);
  short* pak_h    = (short*)carve(sizeof(short) * (size_t)N * 128);
  short* pak_l    = (short*)carve(sizeof(short) * (size_t)N * 128);
  // prepacked bf16 hi/lo weights, MFMA B-fragment order
  short* ph1 = (short*)carve(sizeof(short) * 4096);
  short* pl1 = (short*)carve(sizeof(short) * 4096);
  short* ph2 = (short*)carve(sizeof(short) * 32768);
  short* pl2 = (short*)carve(sizeof(short) * 32768);
  short* ph3 = (short*)carve(sizeof(short) * 32768);
  short* pl3 = (short*)carve(sizeof(short) * 32768);
  short* ph4 = (short*)carve(sizeof(short) * 16384);
  short* pl4 = (short*)carve(sizeof(short) * 16384);

  hipMemsetAsync(deg,     0, sizeof(int) * (size_t)(2 * N), stream);
  hipMemsetAsync(counter, 0, sizeof(int), stream);

  int eb = (E + 255) / 256;
  int nb = (N + 255) / 256;
  deg_count_kernel  <<<eb, 256, 0, stream>>>(ei + E, deg, E);
  base_assign_kernel<<<nb, 256, 0, stream>>>(deg, base, counter, N);
  fill_kernel       <<<eb, 256, 0, stream>>>(ei, ea, base, pos, csr_pack, E);
  prep_w_kernel     <<<42, 256, 0, stream>>>(P[0],  P[2],  ph1, pl1,
                                             P[7],  P[9],  ph2, pl2,
                                             P[14], P[16], ph3, pl3,
                                             P[21], P[23], ph4, pl4);

  int gm    = (N + 63) / 64;  // 64-row MFMA tiles
  int agrid = 2048;           // agg: grid-stride, 8 waves/block

  // layer 1: din=15, H*C=128, ELU; agg writes packed A for gemm2
  gemm_dual_mfma<128, 15><<<gm, 256, 0, stream>>>(x, ph1, pl1, P[1], P[3], xl, xr, N);
  agg_kernel<16><<<agrid, 512, 0, stream>>>(xl, xr, base, deg, csr_pack, P[4], P[5], P[6],
                                            nullptr, pak_h, pak_l,
                                            nullptr, nullptr, nullptr, N, 1);
  // layer 2: din=128, ELU; agg writes packed A for gemm3
  gemm_dual_packed<128><<<gm, 256, 0, stream>>>(pak_h, pak_l, ph2, pl2, P[8], P[10], xl, xr, N);
  agg_kernel<16><<<agrid, 512, 0, stream>>>(xl, xr, base, deg, csr_pack, P[11], P[12], P[13],
                                            nullptr, pak_h, pak_l,
                                            nullptr, nullptr, nullptr, N, 1);
  // layer 3: din=128, ELU; agg writes packed A for gemm4
  gemm_dual_packed<128><<<gm, 256, 0, stream>>>(pak_h, pak_l, ph3, pl3, P[15], P[17], xl, xr, N);
  agg_kernel<16><<<agrid, 512, 0, stream>>>(xl, xr, base, deg, csr_pack, P[18], P[19], P[20],
                                            nullptr, pak_h, pak_l,
                                            nullptr, nullptr, nullptr, N, 1);
  // layer 4: din=128, H*C=64, no ELU + fused final linear 64->1
  gemm_dual_packed<64><<<gm, 256, 0, stream>>>(pak_h, pak_l, ph4, pl4, P[22], P[24], xl, xr, N);
  agg_kernel<8><<<agrid, 512, 0, stream>>>(xl, xr, base, deg, csr_pack, P[25], P[26], P[27],
                                           nullptr, nullptr, nullptr,
                                           Wlin, blin, (float*)d_out, N, 0);
}